// Round 7
// baseline (3053.130 us; speedup 1.0000x reference)
//
#include <hip/hip_runtime.h>
#include <cstdint>
#include <cstddef>

// Problem constants (match reference)
#define NIT    500
#define GAMMA_ 5.0f
#define CC_    1e-3f
#define KAPPA_ 2.0627128075074256f
#define PEN_   100.0f
#define LR_    0.01f

// d_ws layout: pbuf [128 b][2 dir][2 parity][100] f32 = 204800 B, then flags [256] int
#define PBUF_BYTES (128*2*2*100*4)
#define FLAG_COUNT 256

__device__ __forceinline__ float rdlane(float v, int lane) {
  return __int_as_float(__builtin_amdgcn_readlane(__float_as_int(v), lane));
}

// Wave64 sum via DPP (row_shr 1,2,4,8 ; row_bcast15 ; row_bcast31), total in lane 63.
// ~13 VALU ops, ~60 cyc latency. Numerics verified r5 (passed, absmax 1.2e-4).
__device__ __forceinline__ float wred64(float x) {
  int t;
  t = __builtin_amdgcn_update_dpp(0, __float_as_int(x), 0x111, 0xf, 0xf, true); x += __int_as_float(t);
  t = __builtin_amdgcn_update_dpp(0, __float_as_int(x), 0x112, 0xf, 0xf, true); x += __int_as_float(t);
  t = __builtin_amdgcn_update_dpp(0, __float_as_int(x), 0x114, 0xf, 0xf, true); x += __int_as_float(t);
  t = __builtin_amdgcn_update_dpp(0, __float_as_int(x), 0x118, 0xf, 0xf, true); x += __int_as_float(t);
  t = __builtin_amdgcn_update_dpp(0, __float_as_int(x), 0x142, 0xa, 0xf, true); x += __int_as_float(t);
  t = __builtin_amdgcn_update_dpp(0, __float_as_int(x), 0x143, 0xc, 0xf, true); x += __int_as_float(t);
  return rdlane(x, 63);
}

// 256 WGs (grid == CU count -> all resident; r6 proved 512-WG residency fails).
// One WG per (b, half): 6 heads x 2 waves. NO WG-wide barrier in the iteration:
// per-head wave-pair + neighbor-chain sync via LDS acquire/release flags, so the
// 6 heads free-run with skew<=1 and their serial chains interleave on the SIMDs.
__global__ __launch_bounds__(768, 1) void mpo_solver(
    const float* __restrict__ mu, const float* __restrict__ L,
    const float* __restrict__ wprev, const float* __restrict__ climit,
    float* __restrict__ out, float* __restrict__ pbuf, int* __restrict__ flags)
{
  const int tid  = threadIdx.x;
  const int lane = tid & 63;
  const int wave = __builtin_amdgcn_readfirstlane(tid >> 6);  // 0..11
  const int j    = wave >> 1;       // head 0..5
  const int sec  = wave & 1;        // 0 = rows 0-49 + post ("A"), 1 = rows 50-99 ("B")
  const int bid  = blockIdx.x;
  const int b    = bid & 127;
  const int half = bid >> 7;        // 0: heads 0-5, 1: heads 6-11
  const int h    = half * 6 + j;
  const int bh   = b * 12 + h;

  __shared__ float wbuf[2][6][100];   // ring-2 iterate per head
  __shared__ float ybuf[6][100];      // y = S w per head
  __shared__ int   yflag[6];          // B: matvec rows 50-99 of iter k done -> k+1
  __shared__ int   wflag[6];          // A: w(k+1) published in wbuf[(k+1)&1] -> k+1

  const float* Lb = L + (size_t)bh * 10000;

  // ---------- Phase 0: SYRK. Lane owns row r of S = L L^T (fp32, in registers). ----------
  float S[100];
#pragma unroll
  for (int c = 0; c < 100; ++c) S[c] = 0.f;
  const int r = sec * 50 + lane;      // valid row iff lane < 50
  if (lane < 50) {
#pragma unroll 1
    for (int mc = 0; mc < 25; ++mc) {
      float4 lr = *(const float4*)(Lb + r * 100 + mc * 4);
#pragma unroll
      for (int c = 0; c < 100; ++c) {
        const float* Lc = Lb + c * 100 + mc * 4;   // wave-uniform address -> scalar loads
        S[c] = fmaf(lr.x, Lc[0], fmaf(lr.y, Lc[1], fmaf(lr.z, Lc[2], fmaf(lr.w, Lc[3], S[c]))));
      }
    }
  }

  const bool val1 = (lane < 36);
  float mu0 = mu[(size_t)bh * 100 + lane];
  float mu1 = val1 ? mu[(size_t)bh * 100 + 64 + lane] : 0.f;
  float wp0 = wprev[b * 100 + lane];
  float wp1 = val1 ? wprev[b * 100 + 64 + lane] : 0.f;
  float lim = climit[b];

  if (sec == 0) {
    wbuf[0][j][lane] = wp0;
    if (val1) wbuf[0][j][64 + lane] = wp1;
    if (lane == 0) { yflag[j] = 0; wflag[j] = 0; }
  }
  __syncthreads();   // only barrier: publish initial state + flags

  const bool hasNext = (h < 11);
  const bool isPubL  = (half == 0) && (j == 5);  // publishes head 5, consumes head 6
  const bool isPubH  = (half == 1) && (j == 0);  // publishes head 6, consumes head 5
  const int  flagPub = isPubL ? (b * 2 + 0) : (b * 2 + 1);
  const int  flagCon = isPubL ? (b * 2 + 1) : (b * 2 + 0);
  bool dead = false;

  if (sec == 1) {
    // ---------------- B wave: upper-half matvec only ----------------
    for (int k = 0; k < NIT; ++k) {
      if (!dead) {
        long guard = 0;
        while (__hip_atomic_load(&wflag[j], __ATOMIC_ACQUIRE, __HIP_MEMORY_SCOPE_WORKGROUP) < k) {
          __builtin_amdgcn_s_sleep(1);
          if (++guard > (1L << 20)) { dead = true; break; }
        }
      }
      const int p = k & 1;
      float vw0 = wbuf[p][j][lane];
      float vw1 = val1 ? wbuf[p][j][64 + lane] : 0.f;
      float a0 = 0.f, a1 = 0.f, a2 = 0.f, a3 = 0.f;
#pragma unroll
      for (int c = 0; c < 64; c += 4) {
        a0 = fmaf(rdlane(vw0, c + 0), S[c + 0], a0);
        a1 = fmaf(rdlane(vw0, c + 1), S[c + 1], a1);
        a2 = fmaf(rdlane(vw0, c + 2), S[c + 2], a2);
        a3 = fmaf(rdlane(vw0, c + 3), S[c + 3], a3);
      }
#pragma unroll
      for (int c = 64; c < 100; c += 4) {
        a0 = fmaf(rdlane(vw1, c - 64), S[c + 0], a0);
        a1 = fmaf(rdlane(vw1, c - 63), S[c + 1], a1);
        a2 = fmaf(rdlane(vw1, c - 62), S[c + 2], a2);
        a3 = fmaf(rdlane(vw1, c - 61), S[c + 3], a3);
      }
      if (lane < 50) ybuf[j][50 + lane] = (a0 + a2) + (a1 + a3);
      __hip_atomic_store(&yflag[j], k + 1, __ATOMIC_RELEASE, __HIP_MEMORY_SCOPE_WORKGROUP);
    }
  } else {
    // ---------------- A wave: lower-half matvec + post ----------------
    float w0 = wp0, w1 = wp1;         // current iterate lives in registers
    for (int k = 0; k < NIT; ++k) {
      const int p = k & 1;
      {
        float a0 = 0.f, a1 = 0.f, a2 = 0.f, a3 = 0.f;
#pragma unroll
        for (int c = 0; c < 64; c += 4) {
          a0 = fmaf(rdlane(w0, c + 0), S[c + 0], a0);
          a1 = fmaf(rdlane(w0, c + 1), S[c + 1], a1);
          a2 = fmaf(rdlane(w0, c + 2), S[c + 2], a2);
          a3 = fmaf(rdlane(w0, c + 3), S[c + 3], a3);
        }
#pragma unroll
        for (int c = 64; c < 100; c += 4) {
          a0 = fmaf(rdlane(w1, c - 64), S[c + 0], a0);
          a1 = fmaf(rdlane(w1, c - 63), S[c + 1], a1);
          a2 = fmaf(rdlane(w1, c - 62), S[c + 2], a2);
          a3 = fmaf(rdlane(w1, c - 61), S[c + 3], a3);
        }
        if (lane < 50) ybuf[j][lane] = (a0 + a2) + (a1 + a3);
      }

      // non-blocking cross-WG prefetch while waiting for B
      float pf0 = 0.f, pf1 = 0.f;
      bool pfReady = false;
      if ((isPubL || isPubH) && k > 0) {
        if (__hip_atomic_load(&flags[flagCon], __ATOMIC_ACQUIRE, __HIP_MEMORY_SCOPE_AGENT) >= k) {
          const float* src = pbuf + ((size_t)flagCon * 2 + (k & 1)) * 100;
          pf0 = __hip_atomic_load(&src[lane], __ATOMIC_RELAXED, __HIP_MEMORY_SCOPE_AGENT);
          pf1 = val1 ? __hip_atomic_load(&src[64 + lane], __ATOMIC_RELAXED, __HIP_MEMORY_SCOPE_AGENT) : 0.f;
          pfReady = true;
        }
      }

      // wait for B's rows 50-99
      if (!dead) {
        long guard = 0;
        while (__hip_atomic_load(&yflag[j], __ATOMIC_ACQUIRE, __HIP_MEMORY_SCOPE_WORKGROUP) < k + 1) {
          __builtin_amdgcn_s_sleep(1);
          if (++guard > (1L << 20)) { dead = true; break; }
        }
      }
      float y0 = ybuf[j][lane];
      float y1 = val1 ? ybuf[j][64 + lane] : 0.f;

      float ret = wred64(fmaf(mu0, w0, mu1 * w1));
      float s2  = wred64(fmaf(y0, w0, y1 * w1));
      float sigma = sqrtf(s2 + 1e-12f);
      float z     = KAPPA_ * sigma - ret - lim;
      float act   = (z > 0.f) ? 1.f : 0.f;
      float cY    = 2.f * GAMMA_ + act * (PEN_ * KAPPA_ / sigma);
      float cM    = -(1.f + act * PEN_);

      // neighbor iterates (exact k, Jacobi; intra-WG gated by wflag, cross-WG by global flags)
      float wl0, wl1, wn0 = 0.f, wn1 = 0.f;
      if (j == 0) {
        if (half == 0 || k == 0) { wl0 = wp0; wl1 = wp1; }
        else {
          if (!pfReady) {
            if (!dead) {
              long guard = 0;
              while (__hip_atomic_load(&flags[flagCon], __ATOMIC_ACQUIRE, __HIP_MEMORY_SCOPE_AGENT) < k) {
                __builtin_amdgcn_s_sleep(1);
                if (++guard > (1L << 20)) { dead = true; break; }
              }
            }
            const float* src = pbuf + ((size_t)flagCon * 2 + (k & 1)) * 100;
            pf0 = __hip_atomic_load(&src[lane], __ATOMIC_RELAXED, __HIP_MEMORY_SCOPE_AGENT);
            pf1 = val1 ? __hip_atomic_load(&src[64 + lane], __ATOMIC_RELAXED, __HIP_MEMORY_SCOPE_AGENT) : 0.f;
          }
          wl0 = pf0; wl1 = pf1;
        }
      } else {
        if (!dead) {
          long guard = 0;
          while (__hip_atomic_load(&wflag[j - 1], __ATOMIC_ACQUIRE, __HIP_MEMORY_SCOPE_WORKGROUP) < k) {
            __builtin_amdgcn_s_sleep(1);
            if (++guard > (1L << 20)) { dead = true; break; }
          }
        }
        wl0 = wbuf[p][j - 1][lane];
        wl1 = val1 ? wbuf[p][j - 1][64 + lane] : 0.f;
      }
      if (hasNext) {
        if (j == 5) {   // half==0 cross boundary: next is head 6
          if (k == 0) { wn0 = wp0; wn1 = wp1; }
          else {
            if (!pfReady) {
              if (!dead) {
                long guard = 0;
                while (__hip_atomic_load(&flags[flagCon], __ATOMIC_ACQUIRE, __HIP_MEMORY_SCOPE_AGENT) < k) {
                  __builtin_amdgcn_s_sleep(1);
                  if (++guard > (1L << 20)) { dead = true; break; }
                }
              }
              const float* src = pbuf + ((size_t)flagCon * 2 + (k & 1)) * 100;
              pf0 = __hip_atomic_load(&src[lane], __ATOMIC_RELAXED, __HIP_MEMORY_SCOPE_AGENT);
              pf1 = val1 ? __hip_atomic_load(&src[64 + lane], __ATOMIC_RELAXED, __HIP_MEMORY_SCOPE_AGENT) : 0.f;
            }
            wn0 = pf0; wn1 = pf1;
          }
        } else {
          if (!dead) {
            long guard = 0;
            while (__hip_atomic_load(&wflag[j + 1], __ATOMIC_ACQUIRE, __HIP_MEMORY_SCOPE_WORKGROUP) < k) {
              __builtin_amdgcn_s_sleep(1);
              if (++guard > (1L << 20)) { dead = true; break; }
            }
          }
          wn0 = wbuf[p][j + 1][lane];
          wn1 = val1 ? wbuf[p][j + 1][64 + lane] : 0.f;
        }
      }

      float dw0 = w0 - wl0;
      float g0  = fmaf(cM, mu0, cY * y0) + CC_ * (dw0 * rsqrtf(fmaf(dw0, dw0, 1e-10f)));
      if (hasNext) { float dn0 = wn0 - w0; g0 -= CC_ * (dn0 * rsqrtf(fmaf(dn0, dn0, 1e-10f))); }
      float v0 = fmaf(-LR_, g0, w0);
      float v1 = 0.f;
      if (val1) {
        float dw1 = w1 - wl1;
        float g1  = fmaf(cM, mu1, cY * y1) + CC_ * (dw1 * rsqrtf(fmaf(dw1, dw1, 1e-10f)));
        if (hasNext) { float dn1 = wn1 - w1; g1 -= CC_ * (dn1 * rsqrtf(fmaf(dn1, dn1, 1e-10f))); }
        v1 = fmaf(-LR_, g1, w1);
      }

      // ---- Michelot simplex projection (exact, finite convergence) ----
      float a1m   = val1 ? 1.f : 0.f;
      float Ssum  = wred64(v0 + a1m * v1);
      float Cnt   = wred64(1.f + a1m);
      float theta = 0.f;
      for (int it = 0; it < 100; ++it) {
        theta = (Ssum - 1.f) / Cnt;
        float na0 = (v0 > theta) ? 1.f : 0.f;
        float na1 = (val1 && (v1 > theta)) ? 1.f : 0.f;
        float ns = wred64(na0 * v0 + na1 * v1);
        float nc = wred64(na0 + na1);
        if (nc == Cnt) break;
        Ssum = ns; Cnt = nc;
      }
      w0 = fmaxf(v0 - theta, 0.f);
      w1 = val1 ? fmaxf(v1 - theta, 0.f) : 0.f;

      wbuf[1 - p][j][lane] = w0;
      if (val1) wbuf[1 - p][j][64 + lane] = w1;
      __hip_atomic_store(&wflag[j], k + 1, __ATOMIC_RELEASE, __HIP_MEMORY_SCOPE_WORKGROUP);

      if (isPubL || isPubH) {
        float* dst = pbuf + ((size_t)flagPub * 2 + ((k + 1) & 1)) * 100;
        __hip_atomic_store(&dst[lane], w0, __ATOMIC_RELAXED, __HIP_MEMORY_SCOPE_AGENT);
        if (val1) __hip_atomic_store(&dst[64 + lane], w1, __ATOMIC_RELAXED, __HIP_MEMORY_SCOPE_AGENT);
        if (lane == 0)
          __hip_atomic_store(&flags[flagPub], k + 1, __ATOMIC_RELEASE, __HIP_MEMORY_SCOPE_AGENT);
      }
    }

    float* o = out + (size_t)bh * 100;
    o[lane] = w0;
    if (val1) o[64 + lane] = w1;
  }
}

extern "C" void kernel_launch(void* const* d_in, const int* in_sizes, int n_in,
                              void* d_out, int out_size, void* d_ws, size_t ws_size,
                              hipStream_t stream) {
  const float* mu = (const float*)d_in[0];
  const float* L  = (const float*)d_in[1];
  const float* wp = (const float*)d_in[2];
  const float* cl = (const float*)d_in[3];
  float* pbuf  = (float*)d_ws;
  int*   flags = (int*)((char*)d_ws + PBUF_BYTES);
  hipMemsetAsync(flags, 0, FLAG_COUNT * sizeof(int), stream);
  hipLaunchKernelGGL(mpo_solver, dim3(256), dim3(768), 0, stream,
                     mu, L, wp, cl, (float*)d_out, pbuf, flags);
}